// Round 1
// baseline (13196.017 us; speedup 1.0000x reference)
//
#include <hip/hip_runtime.h>

#define EPS_BN 1e-5f

// ---------------------------------------------------------------------------
// Generic row GEMM: C[row][j] (op)= sum_k A[row][k] * (W[k][j]*wscale)
// 256 threads: j = tid&127, r2 = tid>>7 (2 rows per iter). W chunk in LDS.
// phase: 0 = overwrite, 1 = accumulate, 2 = accumulate + channel stats.
// ---------------------------------------------------------------------------
__global__ __launch_bounds__(256) void row_gemm_128(
    const float* __restrict__ A, const float* __restrict__ W, float wscale,
    float* __restrict__ C, int nrows, int phase,
    float* __restrict__ sum_out, float* __restrict__ ssq_out) {
  __shared__ float Wl[128 * 128];
  __shared__ float red[256];
  int tid = threadIdx.x;
  for (int i = tid; i < 128 * 128; i += 256) Wl[i] = W[i] * wscale;
  __syncthreads();
  int j = tid & 127, r2 = tid >> 7;
  float lsum = 0.f, lssq = 0.f;
  for (long rb = (long)blockIdx.x * 2; rb < nrows; rb += (long)gridDim.x * 2) {
    long row = rb + r2;
    if (row < nrows) {
      const float* a = A + row * 128;
      float acc = (phase == 0) ? 0.f : C[row * 128 + j];
      #pragma unroll 8
      for (int k = 0; k < 128; ++k) acc = fmaf(a[k], Wl[k * 128 + j], acc);
      C[row * 128 + j] = acc;
      if (phase == 2) { lsum += acc; lssq += acc * acc; }
    }
  }
  if (phase == 2) {
    if (r2 == 1) { red[j] = lsum; red[128 + j] = lssq; }
    __syncthreads();
    if (r2 == 0) {
      atomicAdd(&sum_out[j], lsum + red[j]);
      atomicAdd(&ssq_out[j], lssq + red[128 + j]);
    }
  }
}

// ---------------------------------------------------------------------------
// u2 = (relu(u1*sc+sh)) @ W, with channel stats.
// ---------------------------------------------------------------------------
__global__ __launch_bounds__(256) void upd_l2_kernel(
    const float* __restrict__ U1, const float* __restrict__ scsh,
    const float* __restrict__ W, float* __restrict__ U2, int nrows,
    float* __restrict__ sum_out, float* __restrict__ ssq_out) {
  __shared__ float Wl[128 * 128];
  __shared__ float scl[128], shl[128];
  __shared__ float red[256];
  int tid = threadIdx.x;
  for (int i = tid; i < 128 * 128; i += 256) Wl[i] = W[i];
  if (tid < 128) { scl[tid] = scsh[tid]; shl[tid] = scsh[128 + tid]; }
  __syncthreads();
  int j = tid & 127, r2 = tid >> 7;
  float lsum = 0.f, lssq = 0.f;
  for (long rb = (long)blockIdx.x * 2; rb < nrows; rb += (long)gridDim.x * 2) {
    long row = rb + r2;
    if (row < nrows) {
      const float* a = U1 + row * 128;
      float acc = 0.f;
      #pragma unroll 4
      for (int k = 0; k < 128; ++k) {
        float ak = fmaxf(fmaf(a[k], scl[k], shl[k]), 0.f);
        acc = fmaf(ak, Wl[k * 128 + j], acc);
      }
      U2[row * 128 + j] = acc;
      lsum += acc; lssq += acc * acc;
    }
  }
  if (r2 == 1) { red[j] = lsum; red[128 + j] = lssq; }
  __syncthreads();
  if (r2 == 0) {
    atomicAdd(&sum_out[j], lsum + red[j]);
    atomicAdd(&ssq_out[j], lssq + red[128 + j]);
  }
}

// ---------------------------------------------------------------------------
// Edge pass 1: stats of z_st, z_ts.  z_st = P[s]+Q[t]+R(ea), z_ts = P[t]+Q[s]+R.
// 256 threads = 2 groups of 128 (2 edges per iter); thread j owns channel j.
// ---------------------------------------------------------------------------
__global__ __launch_bounds__(256) void msg_pass1(
    const float* __restrict__ P, const float* __restrict__ Q,
    const float* __restrict__ EA, const float* __restrict__ W1e,
    const int* __restrict__ SRC, const int* __restrict__ DST, long E,
    float* __restrict__ stats) {
  __shared__ float We[16 * 128];
  __shared__ float red[512];
  int tid = threadIdx.x;
  for (int i = tid; i < 16 * 128; i += 256) We[i] = W1e[i];
  __syncthreads();
  int j = tid & 127, g = tid >> 7;
  float sum_st = 0.f, ssq_st = 0.f, sum_ts = 0.f, ssq_ts = 0.f;
  for (long eb = (long)blockIdx.x * 2; eb < E; eb += (long)gridDim.x * 2) {
    long e = eb + g;
    if (e < E) {
      int s = SRC[e], t = DST[e];
      const float* eap = EA + e * 16;
      float r = 0.f;
      #pragma unroll
      for (int k = 0; k < 16; ++k) r = fmaf(eap[k], We[k * 128 + j], r);
      float zst = P[(long)s * 128 + j] + Q[(long)t * 128 + j] + r;
      float zts = P[(long)t * 128 + j] + Q[(long)s * 128 + j] + r;
      sum_st += zst; ssq_st += zst * zst;
      sum_ts += zts; ssq_ts += zts * zts;
    }
  }
  if (g == 1) { red[j] = sum_st; red[128 + j] = ssq_st; red[256 + j] = sum_ts; red[384 + j] = ssq_ts; }
  __syncthreads();
  if (g == 0) {
    atomicAdd(&stats[j], sum_st + red[j]);
    atomicAdd(&stats[128 + j], ssq_st + red[128 + j]);
    atomicAdd(&stats[256 + j], sum_ts + red[256 + j]);
    atomicAdd(&stats[384 + j], ssq_ts + red[384 + j]);
  }
}

// ---------------------------------------------------------------------------
// Edge pass 2: recompute z, BN1+ReLU -> a, y = a@W2, stats of y.
// ---------------------------------------------------------------------------
__global__ __launch_bounds__(256) void msg_pass2(
    const float* __restrict__ P, const float* __restrict__ Q,
    const float* __restrict__ EA, const float* __restrict__ W1e,
    const float* __restrict__ W2,
    const int* __restrict__ SRC, const int* __restrict__ DST, long E,
    const float* __restrict__ sc1, float* __restrict__ stats2) {
  __shared__ float We[16 * 128];
  __shared__ float W2l[128 * 128];
  __shared__ float al[2][2][128];
  __shared__ float red[512];
  int tid = threadIdx.x;
  for (int i = tid; i < 16 * 128; i += 256) We[i] = W1e[i];
  for (int i = tid; i < 128 * 128; i += 256) W2l[i] = W2[i];
  __syncthreads();
  int j = tid & 127, g = tid >> 7;
  float scst = sc1[j], shst = sc1[128 + j], scts = sc1[256 + j], shts = sc1[384 + j];
  float sum_st = 0.f, ssq_st = 0.f, sum_ts = 0.f, ssq_ts = 0.f;
  for (long eb = (long)blockIdx.x * 2; eb < E; eb += (long)gridDim.x * 2) {
    long e = eb + g;
    bool v = (e < E);
    float ast = 0.f, ats = 0.f;
    if (v) {
      int s = SRC[e], t = DST[e];
      const float* eap = EA + e * 16;
      float r = 0.f;
      #pragma unroll
      for (int k = 0; k < 16; ++k) r = fmaf(eap[k], We[k * 128 + j], r);
      float zst = P[(long)s * 128 + j] + Q[(long)t * 128 + j] + r;
      float zts = P[(long)t * 128 + j] + Q[(long)s * 128 + j] + r;
      ast = fmaxf(fmaf(zst, scst, shst), 0.f);
      ats = fmaxf(fmaf(zts, scts, shts), 0.f);
    }
    al[g][0][j] = ast; al[g][1][j] = ats;
    __syncthreads();
    float yst = 0.f, yts = 0.f;
    #pragma unroll 4
    for (int k = 0; k < 128; ++k) {
      float w = W2l[k * 128 + j];
      yst = fmaf(al[g][0][k], w, yst);
      yts = fmaf(al[g][1][k], w, yts);
    }
    if (v) { sum_st += yst; ssq_st += yst * yst; sum_ts += yts; ssq_ts += yts * yts; }
    __syncthreads();
  }
  if (g == 1) { red[j] = sum_st; red[128 + j] = ssq_st; red[256 + j] = sum_ts; red[384 + j] = ssq_ts; }
  __syncthreads();
  if (g == 0) {
    atomicAdd(&stats2[j], sum_st + red[j]);
    atomicAdd(&stats2[128 + j], ssq_st + red[128 + j]);
    atomicAdd(&stats2[256 + j], sum_ts + red[256 + j]);
    atomicAdd(&stats2[384 + j], ssq_ts + red[384 + j]);
  }
}

// ---------------------------------------------------------------------------
// Edge pass 3: recompute z,y; BN2+ReLU -> m; atomic scatter to a_st/a_ts by src.
// ---------------------------------------------------------------------------
__global__ __launch_bounds__(256) void msg_pass3(
    const float* __restrict__ P, const float* __restrict__ Q,
    const float* __restrict__ EA, const float* __restrict__ W1e,
    const float* __restrict__ W2,
    const int* __restrict__ SRC, const int* __restrict__ DST, long E,
    const float* __restrict__ sc1, const float* __restrict__ sc2,
    float* __restrict__ a_st, float* __restrict__ a_ts) {
  __shared__ float We[16 * 128];
  __shared__ float W2l[128 * 128];
  __shared__ float al[2][2][128];
  int tid = threadIdx.x;
  for (int i = tid; i < 16 * 128; i += 256) We[i] = W1e[i];
  for (int i = tid; i < 128 * 128; i += 256) W2l[i] = W2[i];
  __syncthreads();
  int j = tid & 127, g = tid >> 7;
  float scst = sc1[j], shst = sc1[128 + j], scts = sc1[256 + j], shts = sc1[384 + j];
  float s2st = sc2[j], h2st = sc2[128 + j], s2ts = sc2[256 + j], h2ts = sc2[384 + j];
  for (long eb = (long)blockIdx.x * 2; eb < E; eb += (long)gridDim.x * 2) {
    long e = eb + g;
    bool v = (e < E);
    int s = 0;
    float ast = 0.f, ats = 0.f;
    if (v) {
      s = SRC[e];
      int t = DST[e];
      const float* eap = EA + e * 16;
      float r = 0.f;
      #pragma unroll
      for (int k = 0; k < 16; ++k) r = fmaf(eap[k], We[k * 128 + j], r);
      float zst = P[(long)s * 128 + j] + Q[(long)t * 128 + j] + r;
      float zts = P[(long)t * 128 + j] + Q[(long)s * 128 + j] + r;
      ast = fmaxf(fmaf(zst, scst, shst), 0.f);
      ats = fmaxf(fmaf(zts, scts, shts), 0.f);
    }
    al[g][0][j] = ast; al[g][1][j] = ats;
    __syncthreads();
    float yst = 0.f, yts = 0.f;
    #pragma unroll 4
    for (int k = 0; k < 128; ++k) {
      float w = W2l[k * 128 + j];
      yst = fmaf(al[g][0][k], w, yst);
      yts = fmaf(al[g][1][k], w, yts);
    }
    if (v) {
      float mst = fmaxf(fmaf(yst, s2st, h2st), 0.f);
      float mts = fmaxf(fmaf(yts, s2ts, h2ts), 0.f);
      atomicAdd(&a_st[(long)s * 128 + j], mst);
      atomicAdd(&a_ts[(long)s * 128 + j], mts);
    }
    __syncthreads();
  }
}

// ---------------------------------------------------------------------------
// BN finalize: scale = g*rsqrt(var+eps), shift = be - mean*scale.
// ---------------------------------------------------------------------------
__global__ void bn_finalize(const float* __restrict__ sum, const float* __restrict__ ssq,
                            float invN, const float* __restrict__ g,
                            const float* __restrict__ be,
                            float* __restrict__ sc, float* __restrict__ sh) {
  int j = threadIdx.x;
  float m = sum[j] * invN;
  float v = ssq[j] * invN - m * m;
  float s = g[j] * rsqrtf(v + EPS_BN);
  sc[j] = s;
  sh[j] = be[j] - m * s;
}

// ---------------------------------------------------------------------------
// out = relu(U2*sc + sh)
// ---------------------------------------------------------------------------
__global__ __launch_bounds__(256) void bn_relu_out(
    const float* __restrict__ U2, const float* __restrict__ scsh,
    float* __restrict__ out, long total) {
  long i = (long)blockIdx.x * blockDim.x + threadIdx.x;
  long stride = (long)gridDim.x * blockDim.x;
  for (; i < total; i += stride) {
    int j = (int)(i & 127);
    out[i] = fmaxf(fmaf(U2[i], scsh[j], scsh[128 + j]), 0.f);
  }
}

extern "C" void kernel_launch(void* const* d_in, const int* in_sizes, int n_in,
                              void* d_out, int out_size, void* d_ws, size_t ws_size,
                              hipStream_t stream) {
  const float* h    = (const float*)d_in[0];
  const int*   ei   = (const int*)d_in[1];
  const float* ea   = (const float*)d_in[2];
  const float* mW1  = (const float*)d_in[3];
  const float* mg1  = (const float*)d_in[5];
  const float* mbe1 = (const float*)d_in[6];
  const float* mW2  = (const float*)d_in[7];
  const float* mg2  = (const float*)d_in[9];
  const float* mbe2 = (const float*)d_in[10];
  const float* uW1  = (const float*)d_in[11];
  const float* ug1  = (const float*)d_in[13];
  const float* ube1 = (const float*)d_in[14];
  const float* uW2  = (const float*)d_in[15];
  const float* ug2  = (const float*)d_in[17];
  const float* ube2 = (const float*)d_in[18];

  int n = in_sizes[0] / 128;
  long E = (long)(in_sizes[1] / 2);
  const int* SRC = ei;
  const int* DST = ei + E;

  size_t nf = (size_t)n * 128;
  float* P    = (float*)d_ws;
  float* Q    = P + nf;
  float* a_st = Q + nf;
  float* a_ts = a_st + nf;
  float* st   = a_ts + nf;
  // stats layout (floats):
  //  [0..511]     bn1 sums: sum_st, ssq_st, sum_ts, ssq_ts
  //  [512..1023]  bn2 sums
  //  [1024..1535] bn3 sum/ssq, bn4 sum/ssq
  //  [1536..2047] sc1: sc_st, sh_st, sc_ts, sh_ts
  //  [2048..2559] sc2: sc_st, sh_st, sc_ts, sh_ts
  //  [2560..3071] sc3, sh3, sc4, sh4

  float invE = 1.0f / (float)E;
  float invN = 1.0f / (float)n;

  // zero a_st, a_ts, and all stats sums
  hipMemsetAsync((char*)d_ws + 2 * nf * sizeof(float), 0,
                 (2 * nf + 3072) * sizeof(float), stream);

  // P = h @ W1[0:128], Q = h @ W1[128:256]
  row_gemm_128<<<1024, 256, 0, stream>>>(h, mW1, 1.0f, P, n, 0, nullptr, nullptr);
  row_gemm_128<<<1024, 256, 0, stream>>>(h, mW1 + 128 * 128, 1.0f, Q, n, 0, nullptr, nullptr);

  // BN1 stats over edges
  msg_pass1<<<2048, 256, 0, stream>>>(P, Q, ea, mW1 + 256 * 128, SRC, DST, E, st);
  bn_finalize<<<1, 128, 0, stream>>>(st + 0,   st + 128, invE, mg1, mbe1, st + 1536, st + 1664);
  bn_finalize<<<1, 128, 0, stream>>>(st + 256, st + 384, invE, mg1, mbe1, st + 1792, st + 1920);

  // BN2 stats (recompute z, layer-2 GEMM)
  msg_pass2<<<1024, 256, 0, stream>>>(P, Q, ea, mW1 + 256 * 128, mW2, SRC, DST, E,
                                      st + 1536, st + 512);
  bn_finalize<<<1, 128, 0, stream>>>(st + 512, st + 640, invE, mg2, mbe2, st + 2048, st + 2176);
  bn_finalize<<<1, 128, 0, stream>>>(st + 768, st + 896, invE, mg2, mbe2, st + 2304, st + 2432);

  // recompute + scatter to a_st/a_ts (both by src — faithful to reference)
  msg_pass3<<<1024, 256, 0, stream>>>(P, Q, ea, mW1 + 256 * 128, mW2, SRC, DST, E,
                                      st + 1536, st + 2048, a_st, a_ts);

  // update MLP layer 1: [h | 0.5 a_st | 0.5 a_ts] @ uW1 (3 K-chunks), u1 -> P region
  row_gemm_128<<<1024, 256, 0, stream>>>(h,    uW1,             1.0f, P, n, 0, nullptr, nullptr);
  row_gemm_128<<<1024, 256, 0, stream>>>(a_st, uW1 + 128 * 128, 0.5f, P, n, 1, nullptr, nullptr);
  row_gemm_128<<<1024, 256, 0, stream>>>(a_ts, uW1 + 256 * 128, 0.5f, P, n, 2,
                                         st + 1024, st + 1152);
  bn_finalize<<<1, 128, 0, stream>>>(st + 1024, st + 1152, invN, ug1, ube1, st + 2560, st + 2688);

  // update MLP layer 2: u2 = relu(bn(u1)) @ uW2 -> Q region
  upd_l2_kernel<<<1024, 256, 0, stream>>>(P, st + 2560, uW2, Q, n, st + 1280, st + 1408);
  bn_finalize<<<1, 128, 0, stream>>>(st + 1280, st + 1408, invN, ug2, ube2, st + 2816, st + 2944);

  // final BN+ReLU -> out
  bn_relu_out<<<2048, 256, 0, stream>>>(Q, st + 2816, (float*)d_out, (long)n * 128);
}

// Round 4
// 4451.821 us; speedup vs baseline: 2.9642x; 2.9642x over previous
//
#include <hip/hip_runtime.h>

#define EPS_BN 1e-5f

typedef __bf16 bf16x8 __attribute__((ext_vector_type(8)));
typedef float f32x4 __attribute__((ext_vector_type(4)));

__device__ __forceinline__ unsigned short f2bf(float x) {
  unsigned u = __builtin_bit_cast(unsigned, x);
  unsigned r = (u + 0x7fffu + ((u >> 16) & 1u)) >> 16;
  return (unsigned short)r;
}

__device__ __forceinline__ unsigned long long pack4bf(float a, float b, float c, float d) {
  return (unsigned long long)f2bf(a) | ((unsigned long long)f2bf(b) << 16) |
         ((unsigned long long)f2bf(c) << 32) | ((unsigned long long)f2bf(d) << 48);
}

// ---------------------------------------------------------------------------
// Node-side row GEMM: C[row][j] (op)= sum_k A[row][k]*W[k][j]*wscale
// ---------------------------------------------------------------------------
__global__ __launch_bounds__(256) void row_gemm_128(
    const float* __restrict__ A, const float* __restrict__ W, float wscale,
    float* __restrict__ C, int nrows, int phase,
    float* __restrict__ sum_out, float* __restrict__ ssq_out) {
  __shared__ float Wl[128 * 128];
  __shared__ float red[256];
  int tid = threadIdx.x;
  for (int i = tid; i < 128 * 128; i += 256) Wl[i] = W[i] * wscale;
  __syncthreads();
  int j = tid & 127, r2 = tid >> 7;
  float lsum = 0.f, lssq = 0.f;
  for (long rb = (long)blockIdx.x * 2; rb < nrows; rb += (long)gridDim.x * 2) {
    long row = rb + r2;
    if (row < nrows) {
      const float* a = A + row * 128;
      float acc = (phase == 0) ? 0.f : C[row * 128 + j];
      #pragma unroll 8
      for (int k = 0; k < 128; ++k) acc = fmaf(a[k], Wl[k * 128 + j], acc);
      C[row * 128 + j] = acc;
      if (phase == 2) { lsum += acc; lssq += acc * acc; }
    }
  }
  if (phase == 2) {
    if (r2 == 1) { red[j] = lsum; red[128 + j] = lssq; }
    __syncthreads();
    if (r2 == 0) {
      atomicAdd(&sum_out[j], lsum + red[j]);
      atomicAdd(&ssq_out[j], lssq + red[128 + j]);
    }
  }
}

__global__ __launch_bounds__(256) void upd_l2_kernel(
    const float* __restrict__ U1, const float* __restrict__ scsh,
    const float* __restrict__ W, float* __restrict__ U2, int nrows,
    float* __restrict__ sum_out, float* __restrict__ ssq_out) {
  __shared__ float Wl[128 * 128];
  __shared__ float scl[128], shl[128];
  __shared__ float red[256];
  int tid = threadIdx.x;
  for (int i = tid; i < 128 * 128; i += 256) Wl[i] = W[i];
  if (tid < 128) { scl[tid] = scsh[tid]; shl[tid] = scsh[128 + tid]; }
  __syncthreads();
  int j = tid & 127, r2 = tid >> 7;
  float lsum = 0.f, lssq = 0.f;
  for (long rb = (long)blockIdx.x * 2; rb < nrows; rb += (long)gridDim.x * 2) {
    long row = rb + r2;
    if (row < nrows) {
      const float* a = U1 + row * 128;
      float acc = 0.f;
      #pragma unroll 4
      for (int k = 0; k < 128; ++k) {
        float ak = fmaxf(fmaf(a[k], scl[k], shl[k]), 0.f);
        acc = fmaf(ak, Wl[k * 128 + j], acc);
      }
      U2[row * 128 + j] = acc;
      lsum += acc; lssq += acc * acc;
    }
  }
  if (r2 == 1) { red[j] = lsum; red[128 + j] = lssq; }
  __syncthreads();
  if (r2 == 0) {
    atomicAdd(&sum_out[j], lsum + red[j]);
    atomicAdd(&ssq_out[j], lssq + red[128 + j]);
  }
}

// ---------------------------------------------------------------------------
// BN1 stats over edges, vectorized: 32 threads per edge, float4 per thread.
// ---------------------------------------------------------------------------
__global__ __launch_bounds__(256) void msg_stats1(
    const float* __restrict__ P, const float* __restrict__ Q,
    const float* __restrict__ EA, const float* __restrict__ W1e,
    const int* __restrict__ SRC, const int* __restrict__ DST, long E,
    float* __restrict__ stats) {
  __shared__ float Wel[16][128];
  __shared__ float red[32][16];
  int tid = threadIdx.x;
  for (int i = tid; i < 16 * 128; i += 256) ((float*)Wel)[i] = W1e[i];
  for (int i = tid; i < 512; i += 256) ((float*)red)[i] = 0.f;
  __syncthreads();
  int c4 = tid & 31, grp = tid >> 5;
  const float4* P4 = (const float4*)P;
  const float4* Q4 = (const float4*)Q;
  float4 s_st = {0,0,0,0}, q_st = {0,0,0,0}, s_ts = {0,0,0,0}, q_ts = {0,0,0,0};
  long stride = (long)gridDim.x * 8;
  for (long e = (long)blockIdx.x * 8 + grp; e < E; e += stride) {
    int s = SRC[e], t = DST[e];
    float4 Ps = P4[(long)s * 32 + c4];
    float4 Qt = Q4[(long)t * 32 + c4];
    float4 Pt = P4[(long)t * 32 + c4];
    float4 Qs = Q4[(long)s * 32 + c4];
    float rx = 0.f, ry = 0.f, rz = 0.f, rw = 0.f;
    const float* eap = EA + e * 16;
    #pragma unroll
    for (int k = 0; k < 16; ++k) {
      float f = eap[k];
      const float4 w4 = *(const float4*)&Wel[k][c4 * 4];
      rx = fmaf(f, w4.x, rx); ry = fmaf(f, w4.y, ry);
      rz = fmaf(f, w4.z, rz); rw = fmaf(f, w4.w, rw);
    }
    float zx = Ps.x + Qt.x + rx, zy = Ps.y + Qt.y + ry, zz = Ps.z + Qt.z + rz, zw = Ps.w + Qt.w + rw;
    s_st.x += zx; s_st.y += zy; s_st.z += zz; s_st.w += zw;
    q_st.x += zx * zx; q_st.y += zy * zy; q_st.z += zz * zz; q_st.w += zw * zw;
    float ux = Pt.x + Qs.x + rx, uy = Pt.y + Qs.y + ry, uz = Pt.z + Qs.z + rz, uw = Pt.w + Qs.w + rw;
    s_ts.x += ux; s_ts.y += uy; s_ts.z += uz; s_ts.w += uw;
    q_ts.x += ux * ux; q_ts.y += uy * uy; q_ts.z += uz * uz; q_ts.w += uw * uw;
  }
  atomicAdd(&red[c4][0], s_st.x);  atomicAdd(&red[c4][1], s_st.y);
  atomicAdd(&red[c4][2], s_st.z);  atomicAdd(&red[c4][3], s_st.w);
  atomicAdd(&red[c4][4], q_st.x);  atomicAdd(&red[c4][5], q_st.y);
  atomicAdd(&red[c4][6], q_st.z);  atomicAdd(&red[c4][7], q_st.w);
  atomicAdd(&red[c4][8], s_ts.x);  atomicAdd(&red[c4][9], s_ts.y);
  atomicAdd(&red[c4][10], s_ts.z); atomicAdd(&red[c4][11], s_ts.w);
  atomicAdd(&red[c4][12], q_ts.x); atomicAdd(&red[c4][13], q_ts.y);
  atomicAdd(&red[c4][14], q_ts.z); atomicAdd(&red[c4][15], q_ts.w);
  __syncthreads();
  #pragma unroll
  for (int rep = 0; rep < 2; ++rep) {
    int j = rep * 256 + tid;
    int cc = j >> 4, k = j & 15, group = k >> 2, comp = k & 3;
    atomicAdd(&stats[group * 128 + cc * 4 + comp], red[cc][k]);
  }
}

// ---------------------------------------------------------------------------
// MFMA edge pass. Per 64-edge tile:
//   phase A: z = P[s]+Q[t]+R(ea) (and swapped), BN1+ReLU, bf16 -> LDS A tiles
//   phase B: y = A @ W2 via mfma_f32_16x16x32_bf16
// SCATTER=false: accumulate per-channel sum/ssq of y (BN2 stats).
// SCATTER=true : BN2+ReLU, atomicAdd into a_st/a_ts by src (skip zeros).
// ---------------------------------------------------------------------------
template <bool SCATTER>
__global__ __launch_bounds__(256) void msg_mfma_kernel(
    const float* __restrict__ P, const float* __restrict__ Q,
    const float* __restrict__ EA, const float* __restrict__ W1e,
    const float* __restrict__ W2,
    const int* __restrict__ SRC, const int* __restrict__ DST, long E,
    const float* __restrict__ sc1, const float* __restrict__ sc2,
    float* __restrict__ stats2,
    float* __restrict__ a_st, float* __restrict__ a_ts) {
  __shared__ unsigned short W2T[128][136];   // W2 transposed [n][k], bf16, +16B pad
  __shared__ unsigned short Ast[64][136];    // a_st tile [edge][k]
  __shared__ unsigned short Ats[64][136];
  __shared__ float Wel[16][128];
  __shared__ int sArr[64];

  int tid = threadIdx.x;
  int c4 = tid & 31;       // channel quad for phase A
  int slot = tid >> 5;     // 0..7 edge slot
  int lid = tid & 63;
  int w = tid >> 6;        // wave 0..3
  int lr = lid & 15;       // fragment row/col lane
  int lq = lid >> 4;       // fragment k-group

  // stage W2 transposed (bf16) and W1e
  for (int i = tid; i < 16 * 128; i += 256) ((float*)Wel)[i] = W1e[i];
  #pragma unroll
  for (int i = 0; i < 64; ++i) {
    int idx = i * 256 + tid;
    int k = idx >> 7, n = idx & 127;
    W2T[n][k] = f2bf(W2[idx]);
  }

  // BN1 scale/shift per channel quad
  const float4* sc1v = (const float4*)sc1;
  float4 scst = sc1v[c4], shst = sc1v[32 + c4];
  float4 scts = sc1v[64 + c4], shts = sc1v[96 + c4];

  // BN2 params per (dir, nf) for scatter mode
  float s2st[8], h2st[8], s2ts[8], h2ts[8];
  if constexpr (SCATTER) {
    #pragma unroll
    for (int nf = 0; nf < 8; ++nf) {
      int ch = 16 * nf + lr;
      s2st[nf] = sc2[ch];       h2st[nf] = sc2[128 + ch];
      s2ts[nf] = sc2[256 + ch]; h2ts[nf] = sc2[384 + ch];
    }
  }
  float ssum_st[8], sssq_st[8], ssum_ts[8], sssq_ts[8];
  if constexpr (!SCATTER) {
    #pragma unroll
    for (int nf = 0; nf < 8; ++nf) {
      ssum_st[nf] = 0.f; sssq_st[nf] = 0.f; ssum_ts[nf] = 0.f; sssq_ts[nf] = 0.f;
    }
  }

  const float4* P4 = (const float4*)P;
  const float4* Q4 = (const float4*)Q;

  for (long tb = (long)blockIdx.x * 64; tb < E; tb += (long)gridDim.x * 64) {
    int nE = (int)(E - tb < 64 ? E - tb : 64);
    __syncthreads();   // previous tile's phase B done before overwriting LDS

    // ---- phase A ----
    #pragma unroll 2
    for (int rep = 0; rep < 8; ++rep) {
      int er = rep * 8 + slot;
      if (er < nE) {
        long e = tb + er;
        int s = SRC[e], t = DST[e];
        if (SCATTER && c4 == 0) sArr[er] = s;
        float4 Ps = P4[(long)s * 32 + c4];
        float4 Qt = Q4[(long)t * 32 + c4];
        float4 Pt = P4[(long)t * 32 + c4];
        float4 Qs = Q4[(long)s * 32 + c4];
        float rx = 0.f, ry = 0.f, rz = 0.f, rw = 0.f;
        const float* eap = EA + e * 16;
        #pragma unroll
        for (int k = 0; k < 16; ++k) {
          float f = eap[k];
          const float4 w4 = *(const float4*)&Wel[k][c4 * 4];
          rx = fmaf(f, w4.x, rx); ry = fmaf(f, w4.y, ry);
          rz = fmaf(f, w4.z, rz); rw = fmaf(f, w4.w, rw);
        }
        float ax = fmaxf(fmaf(Ps.x + Qt.x + rx, scst.x, shst.x), 0.f);
        float ay = fmaxf(fmaf(Ps.y + Qt.y + ry, scst.y, shst.y), 0.f);
        float az = fmaxf(fmaf(Ps.z + Qt.z + rz, scst.z, shst.z), 0.f);
        float aw = fmaxf(fmaf(Ps.w + Qt.w + rw, scst.w, shst.w), 0.f);
        *(unsigned long long*)&Ast[er][c4 * 4] = pack4bf(ax, ay, az, aw);
        float bx = fmaxf(fmaf(Pt.x + Qs.x + rx, scts.x, shts.x), 0.f);
        float by = fmaxf(fmaf(Pt.y + Qs.y + ry, scts.y, shts.y), 0.f);
        float bz = fmaxf(fmaf(Pt.z + Qs.z + rz, scts.z, shts.z), 0.f);
        float bw = fmaxf(fmaf(Pt.w + Qs.w + rw, scts.w, shts.w), 0.f);
        *(unsigned long long*)&Ats[er][c4 * 4] = pack4bf(bx, by, bz, bw);
      } else {
        *(unsigned long long*)&Ast[er][c4 * 4] = 0ull;
        *(unsigned long long*)&Ats[er][c4 * 4] = 0ull;
      }
    }
    __syncthreads();

    // ---- phase B: MFMA ----
    int arow = 16 * w + lr;
    const char* astp = (const char*)&Ast[arow][0];
    const char* atsp = (const char*)&Ats[arow][0];
    int acolb = lq * 16;
    bf16x8 afst[4], afts[4];
    #pragma unroll
    for (int ks = 0; ks < 4; ++ks) {
      afst[ks] = *(const bf16x8*)(astp + ks * 64 + acolb);
      afts[ks] = *(const bf16x8*)(atsp + ks * 64 + acolb);
    }
    int srow[4];
    if constexpr (SCATTER) {
      #pragma unroll
      for (int i = 0; i < 4; ++i) {
        int row = 16 * w + 4 * lq + i;
        srow[i] = (row < nE) ? sArr[row] : -1;
      }
    }
    #pragma unroll
    for (int nf = 0; nf < 8; ++nf) {
      f32x4 acc_st = {0.f, 0.f, 0.f, 0.f};
      f32x4 acc_ts = {0.f, 0.f, 0.f, 0.f};
      const char* bp = (const char*)&W2T[16 * nf + lr][0];
      #pragma unroll
      for (int ks = 0; ks < 4; ++ks) {
        bf16x8 bf = *(const bf16x8*)(bp + ks * 64 + acolb);
        acc_st = __builtin_amdgcn_mfma_f32_16x16x32_bf16(afst[ks], bf, acc_st, 0, 0, 0);
        acc_ts = __builtin_amdgcn_mfma_f32_16x16x32_bf16(afts[ks], bf, acc_ts, 0, 0, 0);
      }
      if constexpr (SCATTER) {
        int ch = 16 * nf + lr;
        #pragma unroll
        for (int i = 0; i < 4; ++i) {
          if (srow[i] >= 0) {
            float m1 = fmaxf(fmaf(acc_st[i], s2st[nf], h2st[nf]), 0.f);
            float m2 = fmaxf(fmaf(acc_ts[i], s2ts[nf], h2ts[nf]), 0.f);
            if (m1 > 0.f) atomicAdd(&a_st[(long)srow[i] * 128 + ch], m1);
            if (m2 > 0.f) atomicAdd(&a_ts[(long)srow[i] * 128 + ch], m2);
          }
        }
      } else {
        #pragma unroll
        for (int i = 0; i < 4; ++i) {
          ssum_st[nf] += acc_st[i]; sssq_st[nf] += acc_st[i] * acc_st[i];
          ssum_ts[nf] += acc_ts[i]; sssq_ts[nf] += acc_ts[i] * acc_ts[i];
        }
      }
    }
  }

  if constexpr (!SCATTER) {
    #pragma unroll
    for (int nf = 0; nf < 8; ++nf) {
      float v0 = ssum_st[nf]; v0 += __shfl_xor(v0, 16); v0 += __shfl_xor(v0, 32);
      float v1 = sssq_st[nf]; v1 += __shfl_xor(v1, 16); v1 += __shfl_xor(v1, 32);
      float v2 = ssum_ts[nf]; v2 += __shfl_xor(v2, 16); v2 += __shfl_xor(v2, 32);
      float v3 = sssq_ts[nf]; v3 += __shfl_xor(v3, 16); v3 += __shfl_xor(v3, 32);
      if (lq == 0) {
        int ch = 16 * nf + lr;
        atomicAdd(&stats2[ch], v0);
        atomicAdd(&stats2[128 + ch], v1);
        atomicAdd(&stats2[256 + ch], v2);
        atomicAdd(&stats2[384 + ch], v3);
      }
    }
  }
}

__global__ void bn_finalize(const float* __restrict__ sum, const float* __restrict__ ssq,
                            float invN, const float* __restrict__ g,
                            const float* __restrict__ be,
                            float* __restrict__ sc, float* __restrict__ sh) {
  int j = threadIdx.x;
  float m = sum[j] * invN;
  float v = ssq[j] * invN - m * m;
  float s = g[j] * rsqrtf(v + EPS_BN);
  sc[j] = s;
  sh[j] = be[j] - m * s;
}

__global__ __launch_bounds__(256) void bn_relu_out(
    const float* __restrict__ U2, const float* __restrict__ scsh,
    float* __restrict__ out, long total) {
  long i = (long)blockIdx.x * blockDim.x + threadIdx.x;
  long stride = (long)gridDim.x * blockDim.x;
  for (; i < total; i += stride) {
    int j = (int)(i & 127);
    out[i] = fmaxf(fmaf(U2[i], scsh[j], scsh[128 + j]), 0.f);
  }
}

extern "C" void kernel_launch(void* const* d_in, const int* in_sizes, int n_in,
                              void* d_out, int out_size, void* d_ws, size_t ws_size,
                              hipStream_t stream) {
  const float* h    = (const float*)d_in[0];
  const int*   ei   = (const int*)d_in[1];
  const float* ea   = (const float*)d_in[2];
  const float* mW1  = (const float*)d_in[3];
  const float* mg1  = (const float*)d_in[5];
  const float* mbe1 = (const float*)d_in[6];
  const float* mW2  = (const float*)d_in[7];
  const float* mg2  = (const float*)d_in[9];
  const float* mbe2 = (const float*)d_in[10];
  const float* uW1  = (const float*)d_in[11];
  const float* ug1  = (const float*)d_in[13];
  const float* ube1 = (const float*)d_in[14];
  const float* uW2  = (const float*)d_in[15];
  const float* ug2  = (const float*)d_in[17];
  const float* ube2 = (const float*)d_in[18];

  int n = in_sizes[0] / 128;
  long E = (long)(in_sizes[1] / 2);
  const int* SRC = ei;
  const int* DST = ei + E;

  size_t nf = (size_t)n * 128;
  float* P    = (float*)d_ws;
  float* Q    = P + nf;
  float* a_st = Q + nf;
  float* a_ts = a_st + nf;
  float* st   = a_ts + nf;
  // stats layout (floats):
  //  [0..511]     bn1 sums   [512..1023] bn2 sums   [1024..1535] bn3/bn4 sums
  //  [1536..2047] sc1        [2048..2559] sc2       [2560..3071] sc3/sc4

  float invE = 1.0f / (float)E;
  float invN = 1.0f / (float)n;

  hipMemsetAsync((char*)d_ws + 2 * nf * sizeof(float), 0,
                 (2 * nf + 3072) * sizeof(float), stream);

  // P = h @ W1[0:128], Q = h @ W1[128:256]
  row_gemm_128<<<1024, 256, 0, stream>>>(h, mW1, 1.0f, P, n, 0, nullptr, nullptr);
  row_gemm_128<<<1024, 256, 0, stream>>>(h, mW1 + 128 * 128, 1.0f, Q, n, 0, nullptr, nullptr);

  // BN1 stats over edges
  msg_stats1<<<2048, 256, 0, stream>>>(P, Q, ea, mW1 + 256 * 128, SRC, DST, E, st);
  bn_finalize<<<1, 128, 0, stream>>>(st + 0,   st + 128, invE, mg1, mbe1, st + 1536, st + 1664);
  bn_finalize<<<1, 128, 0, stream>>>(st + 256, st + 384, invE, mg1, mbe1, st + 1792, st + 1920);

  // BN2 stats (recompute z, MFMA layer-2)
  msg_mfma_kernel<false><<<1024, 256, 0, stream>>>(
      P, Q, ea, mW1 + 256 * 128, mW2, SRC, DST, E,
      st + 1536, nullptr, st + 512, nullptr, nullptr);
  bn_finalize<<<1, 128, 0, stream>>>(st + 512, st + 640, invE, mg2, mbe2, st + 2048, st + 2176);
  bn_finalize<<<1, 128, 0, stream>>>(st + 768, st + 896, invE, mg2, mbe2, st + 2304, st + 2432);

  // recompute + BN2+ReLU + scatter
  msg_mfma_kernel<true><<<1024, 256, 0, stream>>>(
      P, Q, ea, mW1 + 256 * 128, mW2, SRC, DST, E,
      st + 1536, st + 2048, nullptr, a_st, a_ts);

  // update MLP layer 1: [h | 0.5 a_st | 0.5 a_ts] @ uW1, u1 -> P region
  row_gemm_128<<<1024, 256, 0, stream>>>(h,    uW1,             1.0f, P, n, 0, nullptr, nullptr);
  row_gemm_128<<<1024, 256, 0, stream>>>(a_st, uW1 + 128 * 128, 0.5f, P, n, 1, nullptr, nullptr);
  row_gemm_128<<<1024, 256, 0, stream>>>(a_ts, uW1 + 256 * 128, 0.5f, P, n, 2,
                                         st + 1024, st + 1152);
  bn_finalize<<<1, 128, 0, stream>>>(st + 1024, st + 1152, invN, ug1, ube1, st + 2560, st + 2688);

  // update MLP layer 2
  upd_l2_kernel<<<1024, 256, 0, stream>>>(P, st + 2560, uW2, Q, n, st + 1280, st + 1408);
  bn_finalize<<<1, 128, 0, stream>>>(st + 1280, st + 1408, invN, ug2, ube2, st + 2816, st + 2944);

  bn_relu_out<<<2048, 256, 0, stream>>>(Q, st + 2816, (float*)d_out, (long)n * 128);
}

// Round 5
// 2902.133 us; speedup vs baseline: 4.5470x; 1.5340x over previous
//
#include <hip/hip_runtime.h>

#define EPS_BN 1e-5f

typedef __bf16 bf16x8 __attribute__((ext_vector_type(8)));
typedef float f32x4 __attribute__((ext_vector_type(4)));
typedef unsigned short us8 __attribute__((ext_vector_type(8)));
typedef unsigned int u32x4 __attribute__((ext_vector_type(4)));

__device__ __forceinline__ unsigned short f2bf(float x) {
  unsigned u = __builtin_bit_cast(unsigned, x);
  unsigned r = (u + 0x7fffu + ((u >> 16) & 1u)) >> 16;
  return (unsigned short)r;
}
__device__ __forceinline__ unsigned pack2bf(float a, float b) {
  return (unsigned)f2bf(a) | ((unsigned)f2bf(b) << 16);
}
__device__ __forceinline__ unsigned long long pack4bf(float a, float b, float c, float d) {
  return (unsigned long long)pack2bf(a, b) | ((unsigned long long)pack2bf(c, d) << 32);
}
__device__ __forceinline__ float ubf(unsigned short u) {
  return __builtin_bit_cast(float, (unsigned)u << 16);
}

// ---------------------------------------------------------------------------
// Node MFMA GEMM: C[n x 128] = sum_c A_c[n x 128] @ (W_c[128x128] * s_c)
// W chunks contiguous at W + c*16384. dostats: accumulate channel sum/ssq.
// grid = ceil(n/64) blocks, 256 threads (4 waves x 16 rows).
// ---------------------------------------------------------------------------
template <bool ABF16>
__global__ __launch_bounds__(256) void node_mfma(
    const void* A0, const void* A1, const void* A2,
    const float* __restrict__ W, float s0, float s1, float s2,
    float* __restrict__ C, int n, int dostats,
    float* __restrict__ sum_out, float* __restrict__ ssq_out, int nk) {
  __shared__ unsigned short WT[128][136];
  int tid = threadIdx.x;
  int lid = tid & 63, w = tid >> 6, lr = lid & 15, lq = lid >> 4;
  long rbase = (long)blockIdx.x * 64 + 16 * w;

  const void* As[3] = {A0, A1, A2};
  float ss[3] = {s0, s1, s2};
  f32x4 acc[8];
  #pragma unroll
  for (int nf = 0; nf < 8; ++nf) acc[nf] = f32x4{0.f, 0.f, 0.f, 0.f};

  long r = rbase + lr;
  bool rv = (r < n);
  long rl = rv ? r : 0;

  for (int c = 0; c < nk; ++c) {
    if (c) __syncthreads();
    const float* Wc = W + (long)c * 16384;
    float sc = ss[c];
    for (int i = tid; i < 16384; i += 256) {
      int k = i >> 7, cc = i & 127;
      WT[cc][k] = f2bf(Wc[i] * sc);
    }
    __syncthreads();

    bf16x8 af[4];
    if (ABF16) {
      const us8* Ar = (const us8*)((const unsigned short*)As[c] + rl * 128);
      #pragma unroll
      for (int ks = 0; ks < 4; ++ks) {
        us8 v = Ar[ks * 4 + lq];
        if (!rv) v = us8{0, 0, 0, 0, 0, 0, 0, 0};
        af[ks] = __builtin_bit_cast(bf16x8, v);
      }
    } else {
      const float* Ar = (const float*)As[c] + rl * 128;
      #pragma unroll
      for (int ks = 0; ks < 4; ++ks) {
        int e0 = 32 * ks + 8 * lq;
        float4 x = *(const float4*)(Ar + e0);
        float4 y = *(const float4*)(Ar + e0 + 4);
        u32x4 t;
        t[0] = pack2bf(x.x, x.y); t[1] = pack2bf(x.z, x.w);
        t[2] = pack2bf(y.x, y.y); t[3] = pack2bf(y.z, y.w);
        if (!rv) { t[0] = 0; t[1] = 0; t[2] = 0; t[3] = 0; }
        af[ks] = __builtin_bit_cast(bf16x8, t);
      }
    }
    #pragma unroll
    for (int nf = 0; nf < 8; ++nf) {
      const char* bp = (const char*)&WT[16 * nf + lr][0];
      #pragma unroll
      for (int ks = 0; ks < 4; ++ks) {
        bf16x8 bf = *(const bf16x8*)(bp + ks * 64 + lq * 16);
        acc[nf] = __builtin_amdgcn_mfma_f32_16x16x32_bf16(af[ks], bf, acc[nf], 0, 0, 0);
      }
    }
  }

  float lsum[8], lssq[8];
  #pragma unroll
  for (int nf = 0; nf < 8; ++nf) { lsum[nf] = 0.f; lssq[nf] = 0.f; }
  #pragma unroll
  for (int nf = 0; nf < 8; ++nf) {
    #pragma unroll
    for (int i = 0; i < 4; ++i) {
      long nd = rbase + 4 * lq + i;
      if (nd < n) {
        float v = acc[nf][i];
        C[nd * 128 + 16 * nf + lr] = v;
        lsum[nf] += v; lssq[nf] += v * v;
      }
    }
  }
  if (dostats) {
    #pragma unroll
    for (int nf = 0; nf < 8; ++nf) {
      float v0 = lsum[nf]; v0 += __shfl_xor(v0, 16); v0 += __shfl_xor(v0, 32);
      float v1 = lssq[nf]; v1 += __shfl_xor(v1, 16); v1 += __shfl_xor(v1, 32);
      if (lq == 0) {
        atomicAdd(&sum_out[16 * nf + lr], v0);
        atomicAdd(&ssq_out[16 * nf + lr], v1);
      }
    }
  }
}

// ---------------------------------------------------------------------------
// BN1 stats over edges (raw z), fp32 P/Q gathers + VALU edge-attr GEMM.
// ---------------------------------------------------------------------------
__global__ __launch_bounds__(256) void msg_stats1(
    const float* __restrict__ P, const float* __restrict__ Q,
    const float* __restrict__ EA, const float* __restrict__ W1e,
    const int* __restrict__ SRC, const int* __restrict__ DST, long E,
    float* __restrict__ stats) {
  __shared__ float Wel[16][128];
  __shared__ float red[32][16];
  int tid = threadIdx.x;
  for (int i = tid; i < 16 * 128; i += 256) ((float*)Wel)[i] = W1e[i];
  for (int i = tid; i < 512; i += 256) ((float*)red)[i] = 0.f;
  __syncthreads();
  int c4 = tid & 31, grp = tid >> 5;
  const float4* P4 = (const float4*)P;
  const float4* Q4 = (const float4*)Q;
  float4 s_st = {0,0,0,0}, q_st = {0,0,0,0}, s_ts = {0,0,0,0}, q_ts = {0,0,0,0};
  long stride = (long)gridDim.x * 8;
  for (long e = (long)blockIdx.x * 8 + grp; e < E; e += stride) {
    int s = SRC[e], t = DST[e];
    float4 Ps = P4[(long)s * 32 + c4];
    float4 Qt = Q4[(long)t * 32 + c4];
    float4 Pt = P4[(long)t * 32 + c4];
    float4 Qs = Q4[(long)s * 32 + c4];
    float rx = 0.f, ry = 0.f, rz = 0.f, rw = 0.f;
    const float* eap = EA + e * 16;
    #pragma unroll
    for (int k = 0; k < 16; ++k) {
      float f = eap[k];
      const float4 w4 = *(const float4*)&Wel[k][c4 * 4];
      rx = fmaf(f, w4.x, rx); ry = fmaf(f, w4.y, ry);
      rz = fmaf(f, w4.z, rz); rw = fmaf(f, w4.w, rw);
    }
    float zx = Ps.x + Qt.x + rx, zy = Ps.y + Qt.y + ry, zz = Ps.z + Qt.z + rz, zw = Ps.w + Qt.w + rw;
    s_st.x += zx; s_st.y += zy; s_st.z += zz; s_st.w += zw;
    q_st.x += zx * zx; q_st.y += zy * zy; q_st.z += zz * zz; q_st.w += zw * zw;
    float ux = Pt.x + Qs.x + rx, uy = Pt.y + Qs.y + ry, uz = Pt.z + Qs.z + rz, uw = Pt.w + Qs.w + rw;
    s_ts.x += ux; s_ts.y += uy; s_ts.z += uz; s_ts.w += uw;
    q_ts.x += ux * ux; q_ts.y += uy * uy; q_ts.z += uz * uz; q_ts.w += uw * uw;
  }
  atomicAdd(&red[c4][0], s_st.x);  atomicAdd(&red[c4][1], s_st.y);
  atomicAdd(&red[c4][2], s_st.z);  atomicAdd(&red[c4][3], s_st.w);
  atomicAdd(&red[c4][4], q_st.x);  atomicAdd(&red[c4][5], q_st.y);
  atomicAdd(&red[c4][6], q_st.z);  atomicAdd(&red[c4][7], q_st.w);
  atomicAdd(&red[c4][8], s_ts.x);  atomicAdd(&red[c4][9], s_ts.y);
  atomicAdd(&red[c4][10], s_ts.z); atomicAdd(&red[c4][11], s_ts.w);
  atomicAdd(&red[c4][12], q_ts.x); atomicAdd(&red[c4][13], q_ts.y);
  atomicAdd(&red[c4][14], q_ts.z); atomicAdd(&red[c4][15], q_ts.w);
  __syncthreads();
  #pragma unroll
  for (int rep = 0; rep < 2; ++rep) {
    int j = rep * 256 + tid;
    int cc = j >> 4, k = j & 15, group = k >> 2, comp = k & 3;
    atomicAdd(&stats[group * 128 + cc * 4 + comp], red[cc][k]);
  }
}

// ---------------------------------------------------------------------------
// Prescale node table: outA = bf16(X*sca[ch]), outB = bf16(X*scb[ch]).
// ---------------------------------------------------------------------------
__global__ __launch_bounds__(256) void prescale_pq(
    const float* __restrict__ X, const float* __restrict__ sca,
    const float* __restrict__ scb,
    unsigned* __restrict__ outA, unsigned* __restrict__ outB, long nrows) {
  long gid = (long)blockIdx.x * 256 + threadIdx.x;
  int c2 = (int)(gid & 63);
  float a0 = sca[2 * c2], a1 = sca[2 * c2 + 1];
  float b0 = scb[2 * c2], b1 = scb[2 * c2 + 1];
  const float2* X2 = (const float2*)X;
  long rstride = ((long)gridDim.x * 256) >> 6;
  for (long row = gid >> 6; row < nrows; row += rstride) {
    float2 x = X2[row * 64 + c2];
    outA[row * 64 + c2] = pack2bf(x.x * a0, x.y * a1);
    outB[row * 64 + c2] = pack2bf(x.x * b0, x.y * b1);
  }
}

// u1' = bf16(relu(u1*sc[ch] + sc[128+ch]))
__global__ __launch_bounds__(256) void prescale_relu(
    const float* __restrict__ X, const float* __restrict__ scsh,
    unsigned* __restrict__ out, long nrows) {
  long gid = (long)blockIdx.x * 256 + threadIdx.x;
  int c2 = (int)(gid & 63);
  float s0 = scsh[2 * c2], s1 = scsh[2 * c2 + 1];
  float h0 = scsh[128 + 2 * c2], h1 = scsh[128 + 2 * c2 + 1];
  const float2* X2 = (const float2*)X;
  long rstride = ((long)gridDim.x * 256) >> 6;
  for (long row = gid >> 6; row < nrows; row += rstride) {
    float2 x = X2[row * 64 + c2];
    out[row * 64 + c2] = pack2bf(fmaxf(fmaf(x.x, s0, h0), 0.f),
                                 fmaxf(fmaf(x.y, s1, h1), 0.f));
  }
}

// ---------------------------------------------------------------------------
// R~_d[e][ch] = bf16( sc_d[ch]*(ea[e]@We)[ch] + sh_d[ch] ), both directions.
// sc1 layout: [sc_st(128) | sh_st | sc_ts | sh_ts]
// ---------------------------------------------------------------------------
__global__ __launch_bounds__(256) void rmat_scaled(
    const float* __restrict__ EA, const float* __restrict__ W1e,
    const float* __restrict__ sc1,
    unsigned* __restrict__ Rst, unsigned* __restrict__ Rts, long E) {
  long gid = (long)blockIdx.x * 256 + threadIdx.x;
  int c2 = (int)(gid & 63);
  int ch = 2 * c2;
  float wa[16], wb[16];
  #pragma unroll
  for (int k = 0; k < 16; ++k) { wa[k] = W1e[k * 128 + ch]; wb[k] = W1e[k * 128 + ch + 1]; }
  float sa_st = sc1[ch],       sb_st = sc1[ch + 1];
  float ha_st = sc1[128 + ch], hb_st = sc1[128 + ch + 1];
  float sa_ts = sc1[256 + ch], sb_ts = sc1[256 + ch + 1];
  float ha_ts = sc1[384 + ch], hb_ts = sc1[384 + ch + 1];
  long estride = ((long)gridDim.x * 256) >> 6;
  for (long e = gid >> 6; e < E; e += estride) {
    const float* eap = EA + e * 16;
    float ra = 0.f, rb = 0.f;
    #pragma unroll
    for (int k = 0; k < 16; ++k) { ra = fmaf(eap[k], wa[k], ra); rb = fmaf(eap[k], wb[k], rb); }
    Rst[e * 64 + c2] = pack2bf(fmaf(ra, sa_st, ha_st), fmaf(rb, sb_st, hb_st));
    Rts[e * 64 + c2] = pack2bf(fmaf(ra, sa_ts, ha_ts), fmaf(rb, sb_ts, hb_ts));
  }
}

// ---------------------------------------------------------------------------
// Fast edge MFMA pass: register-assembled A-frags, no main-loop barriers.
// a_st = relu(Pst[s]+Qst[t]+Rst[e]); y = a@W2 (MFMA).
// SCATTER=false: channel stats of y. true: BN2+ReLU + atomic scatter by src.
// ---------------------------------------------------------------------------
template <bool SCATTER>
__global__ __launch_bounds__(256) void msg2(
    const unsigned short* __restrict__ Pst, const unsigned short* __restrict__ Qst,
    const unsigned short* __restrict__ Pts, const unsigned short* __restrict__ Qts,
    const unsigned short* __restrict__ Rst, const unsigned short* __restrict__ Rts,
    const float* __restrict__ W2,
    const int* __restrict__ SRC, const int* __restrict__ DST, long E,
    const float* __restrict__ sc2, float* __restrict__ stats2,
    float* __restrict__ a_st, float* __restrict__ a_ts) {
  __shared__ unsigned short W2T[128][136];
  int tid = threadIdx.x;
  for (int i = tid; i < 16384; i += 256) {
    int k = i >> 7, c = i & 127;
    W2T[c][k] = f2bf(W2[i]);
  }
  __syncthreads();
  int lid = tid & 63, w = tid >> 6, lr = lid & 15, lq = lid >> 4;

  float s2st[8], h2st[8], s2ts[8], h2ts[8];
  float sum_st[8], ssq_st[8], sum_ts[8], ssq_ts[8];
  if constexpr (SCATTER) {
    #pragma unroll
    for (int nf = 0; nf < 8; ++nf) {
      int ch = 16 * nf + lr;
      s2st[nf] = sc2[ch];       h2st[nf] = sc2[128 + ch];
      s2ts[nf] = sc2[256 + ch]; h2ts[nf] = sc2[384 + ch];
    }
  } else {
    #pragma unroll
    for (int nf = 0; nf < 8; ++nf) {
      sum_st[nf] = 0.f; ssq_st[nf] = 0.f; sum_ts[nf] = 0.f; ssq_ts[nf] = 0.f;
    }
  }

  for (long wbase = (long)blockIdx.x * 64 + 16 * w; wbase < E;
       wbase += (long)gridDim.x * 64) {
    long e = wbase + lr;
    bool ev = (e < E);
    long el = ev ? e : (E - 1);
    int s = SRC[el], t = DST[el];
    const us8* PstR = (const us8*)(Pst + (long)s * 128);
    const us8* QstR = (const us8*)(Qst + (long)t * 128);
    const us8* PtsR = (const us8*)(Pts + (long)t * 128);
    const us8* QtsR = (const us8*)(Qts + (long)s * 128);
    const us8* RstR = (const us8*)(Rst + el * 128);
    const us8* RtsR = (const us8*)(Rts + el * 128);

    bf16x8 afst[4], afts[4];
    #pragma unroll
    for (int ks = 0; ks < 4; ++ks) {
      int ci = ks * 4 + lq;
      us8 p1 = PstR[ci], q1 = QstR[ci], r1 = RstR[ci];
      us8 p2 = PtsR[ci], q2 = QtsR[ci], r2 = RtsR[ci];
      u32x4 t1, t2;
      #pragma unroll
      for (int jj = 0; jj < 4; ++jj) {
        float a0 = fmaxf(ubf(p1[2 * jj]) + ubf(q1[2 * jj]) + ubf(r1[2 * jj]), 0.f);
        float a1 = fmaxf(ubf(p1[2 * jj + 1]) + ubf(q1[2 * jj + 1]) + ubf(r1[2 * jj + 1]), 0.f);
        float b0 = fmaxf(ubf(p2[2 * jj]) + ubf(q2[2 * jj]) + ubf(r2[2 * jj]), 0.f);
        float b1 = fmaxf(ubf(p2[2 * jj + 1]) + ubf(q2[2 * jj + 1]) + ubf(r2[2 * jj + 1]), 0.f);
        t1[jj] = pack2bf(a0, a1);
        t2[jj] = pack2bf(b0, b1);
      }
      if (!ev) { t1[0]=0; t1[1]=0; t1[2]=0; t1[3]=0; t2[0]=0; t2[1]=0; t2[2]=0; t2[3]=0; }
      afst[ks] = __builtin_bit_cast(bf16x8, t1);
      afts[ks] = __builtin_bit_cast(bf16x8, t2);
    }

    int srow[4];
    if constexpr (SCATTER) {
      #pragma unroll
      for (int i = 0; i < 4; ++i) {
        long er = wbase + 4 * lq + i;
        srow[i] = (er < E) ? SRC[er] : -1;
      }
    }

    #pragma unroll
    for (int nf = 0; nf < 8; ++nf) {
      f32x4 acc_st = {0.f, 0.f, 0.f, 0.f};
      f32x4 acc_ts = {0.f, 0.f, 0.f, 0.f};
      const char* bp = (const char*)&W2T[16 * nf + lr][0];
      #pragma unroll
      for (int ks = 0; ks < 4; ++ks) {
        bf16x8 bf = *(const bf16x8*)(bp + ks * 64 + lq * 16);
        acc_st = __builtin_amdgcn_mfma_f32_16x16x32_bf16(afst[ks], bf, acc_st, 0, 0, 0);
        acc_ts = __builtin_amdgcn_mfma_f32_16x16x32_bf16(afts[ks], bf, acc_ts, 0, 0, 0);
      }
      if constexpr (SCATTER) {
        int ch = 16 * nf + lr;
        #pragma unroll
        for (int i = 0; i < 4; ++i) {
          if (srow[i] >= 0) {
            float m1 = fmaxf(fmaf(acc_st[i], s2st[nf], h2st[nf]), 0.f);
            float m2 = fmaxf(fmaf(acc_ts[i], s2ts[nf], h2ts[nf]), 0.f);
            if (m1 > 0.f) atomicAdd(&a_st[(long)srow[i] * 128 + ch], m1);
            if (m2 > 0.f) atomicAdd(&a_ts[(long)srow[i] * 128 + ch], m2);
          }
        }
      } else {
        #pragma unroll
        for (int i = 0; i < 4; ++i) {
          sum_st[nf] += acc_st[i]; ssq_st[nf] += acc_st[i] * acc_st[i];
          sum_ts[nf] += acc_ts[i]; ssq_ts[nf] += acc_ts[i] * acc_ts[i];
        }
      }
    }
  }

  if constexpr (!SCATTER) {
    #pragma unroll
    for (int nf = 0; nf < 8; ++nf) {
      float v0 = sum_st[nf]; v0 += __shfl_xor(v0, 16); v0 += __shfl_xor(v0, 32);
      float v1 = ssq_st[nf]; v1 += __shfl_xor(v1, 16); v1 += __shfl_xor(v1, 32);
      float v2 = sum_ts[nf]; v2 += __shfl_xor(v2, 16); v2 += __shfl_xor(v2, 32);
      float v3 = ssq_ts[nf]; v3 += __shfl_xor(v3, 16); v3 += __shfl_xor(v3, 32);
      if (lq == 0) {
        int ch = 16 * nf + lr;
        atomicAdd(&stats2[ch], v0);
        atomicAdd(&stats2[128 + ch], v1);
        atomicAdd(&stats2[256 + ch], v2);
        atomicAdd(&stats2[384 + ch], v3);
      }
    }
  }
}

// ---------------------------------------------------------------------------
// FALLBACK edge MFMA pass (R4 version): fp32 P/Q gathers, LDS A-tiles.
// ---------------------------------------------------------------------------
template <bool SCATTER>
__global__ __launch_bounds__(256) void msg_mfma_kernel(
    const float* __restrict__ P, const float* __restrict__ Q,
    const float* __restrict__ EA, const float* __restrict__ W1e,
    const float* __restrict__ W2,
    const int* __restrict__ SRC, const int* __restrict__ DST, long E,
    const float* __restrict__ sc1, const float* __restrict__ sc2,
    float* __restrict__ stats2,
    float* __restrict__ a_st, float* __restrict__ a_ts) {
  __shared__ unsigned short W2T[128][136];
  __shared__ unsigned short Ast[64][136];
  __shared__ unsigned short Ats[64][136];
  __shared__ float Wel[16][128];
  __shared__ int sArr[64];

  int tid = threadIdx.x;
  int c4 = tid & 31;
  int slot = tid >> 5;
  int lid = tid & 63;
  int w = tid >> 6;
  int lr = lid & 15;
  int lq = lid >> 4;

  for (int i = tid; i < 16 * 128; i += 256) ((float*)Wel)[i] = W1e[i];
  #pragma unroll
  for (int i = 0; i < 64; ++i) {
    int idx = i * 256 + tid;
    int k = idx >> 7, n = idx & 127;
    W2T[n][k] = f2bf(W2[idx]);
  }

  const float4* sc1v = (const float4*)sc1;
  float4 scst = sc1v[c4], shst = sc1v[32 + c4];
  float4 scts = sc1v[64 + c4], shts = sc1v[96 + c4];

  float s2st[8], h2st[8], s2ts[8], h2ts[8];
  if constexpr (SCATTER) {
    #pragma unroll
    for (int nf = 0; nf < 8; ++nf) {
      int ch = 16 * nf + lr;
      s2st[nf] = sc2[ch];       h2st[nf] = sc2[128 + ch];
      s2ts[nf] = sc2[256 + ch]; h2ts[nf] = sc2[384 + ch];
    }
  }
  float ssum_st[8], sssq_st[8], ssum_ts[8], sssq_ts[8];
  if constexpr (!SCATTER) {
    #pragma unroll
    for (int nf = 0; nf < 8; ++nf) {
      ssum_st[nf] = 0.f; sssq_st[nf] = 0.f; ssum_ts[nf] = 0.f; sssq_ts[nf] = 0.f;
    }
  }

  const float4* P4 = (const float4*)P;
  const float4* Q4 = (const float4*)Q;

  for (long tb = (long)blockIdx.x * 64; tb < E; tb += (long)gridDim.x * 64) {
    int nE = (int)(E - tb < 64 ? E - tb : 64);
    __syncthreads();
    #pragma unroll 2
    for (int rep = 0; rep < 8; ++rep) {
      int er = rep * 8 + slot;
      if (er < nE) {
        long e = tb + er;
        int s = SRC[e], t = DST[e];
        if (SCATTER && c4 == 0) sArr[er] = s;
        float4 Ps = P4[(long)s * 32 + c4];
        float4 Qt = Q4[(long)t * 32 + c4];
        float4 Pt = P4[(long)t * 32 + c4];
        float4 Qs = Q4[(long)s * 32 + c4];
        float rx = 0.f, ry = 0.f, rz = 0.f, rw = 0.f;
        const float* eap = EA + e * 16;
        #pragma unroll
        for (int k = 0; k < 16; ++k) {
          float f = eap[k];
          const float4 w4 = *(const float4*)&Wel[k][c4 * 4];
          rx = fmaf(f, w4.x, rx); ry = fmaf(f, w4.y, ry);
          rz = fmaf(f, w4.z, rz); rw = fmaf(f, w4.w, rw);
        }
        float ax = fmaxf(fmaf(Ps.x + Qt.x + rx, scst.x, shst.x), 0.f);
        float ay = fmaxf(fmaf(Ps.y + Qt.y + ry, scst.y, shst.y), 0.f);
        float az = fmaxf(fmaf(Ps.z + Qt.z + rz, scst.z, shst.z), 0.f);
        float aw = fmaxf(fmaf(Ps.w + Qt.w + rw, scst.w, shst.w), 0.f);
        *(unsigned long long*)&Ast[er][c4 * 4] = pack4bf(ax, ay, az, aw);
        float bx = fmaxf(fmaf(Pt.x + Qs.x + rx, scts.x, shts.x), 0.f);
        float by = fmaxf(fmaf(Pt.y + Qs.y + ry, scts.y, shts.y), 0.f);
        float bz = fmaxf(fmaf(Pt.z + Qs.z + rz, scts.z, shts.z), 0.f);
        float bw = fmaxf(fmaf(Pt.w + Qs.w + rw, scts.w, shts.w), 0.f);
        *(unsigned long long*)&Ats[er][c4 * 4] = pack4bf(bx, by, bz, bw);
      } else {
        *(unsigned long long*)&Ast[er][c4 * 4] = 0ull;
        *(unsigned long long*)&Ats[er][c4 * 4] = 0ull;
      }
    }
    __syncthreads();

    int arow = 16 * w + lr;
    const char* astp = (const char*)&Ast[arow][0];
    const char* atsp = (const char*)&Ats[arow][0];
    int acolb = lq * 16;
    bf16x8 afst[4], afts[4];
    #pragma unroll
    for (int ks = 0; ks < 4; ++ks) {
      afst[ks] = *(const bf16x8*)(astp + ks * 64 + acolb);
      afts[ks] = *(const bf16x8*)(atsp + ks * 64 + acolb);
    }
    int srow[4];
    if constexpr (SCATTER) {
      #pragma unroll
      for (int i = 0; i < 4; ++i) {
        int row = 16 * w + 4 * lq + i;
        srow[i] = (row < nE) ? sArr[row] : -1;
      }
    }
    #pragma unroll
    for (int nf = 0; nf < 8; ++nf) {
      f32x4 acc_st = {0.f, 0.f, 0.f, 0.f};
      f32x4 acc_ts = {0.f, 0.f, 0.f, 0.f};
      const char* bp = (const char*)&W2T[16 * nf + lr][0];
      #pragma unroll
      for (int ks = 0; ks < 4; ++ks) {
        bf16x8 bf = *(const bf16x8*)(bp + ks * 64 + acolb);
        acc_st = __builtin_amdgcn_mfma_f32_16x16x32_bf16(afst[ks], bf, acc_st, 0, 0, 0);
        acc_ts = __builtin_amdgcn_mfma_f32_16x16x32_bf16(afts[ks], bf, acc_ts, 0, 0, 0);
      }
      if constexpr (SCATTER) {
        int ch = 16 * nf + lr;
        #pragma unroll
        for (int i = 0; i < 4; ++i) {
          if (srow[i] >= 0) {
            float m1 = fmaxf(fmaf(acc_st[i], s2st[nf], h2st[nf]), 0.f);
            float m2 = fmaxf(fmaf(acc_ts[i], s2ts[nf], h2ts[nf]), 0.f);
            if (m1 > 0.f) atomicAdd(&a_st[(long)srow[i] * 128 + ch], m1);
            if (m2 > 0.f) atomicAdd(&a_ts[(long)srow[i] * 128 + ch], m2);
          }
        }
      } else {
        #pragma unroll
        for (int i = 0; i < 4; ++i) {
          ssum_st[nf] += acc_st[i]; sssq_st[nf] += acc_st[i] * acc_st[i];
          ssum_ts[nf] += acc_ts[i]; sssq_ts[nf] += acc_ts[i] * acc_ts[i];
        }
      }
    }
  }

  if constexpr (!SCATTER) {
    #pragma unroll
    for (int nf = 0; nf < 8; ++nf) {
      float v0 = ssum_st[nf]; v0 += __shfl_xor(v0, 16); v0 += __shfl_xor(v0, 32);
      float v1 = sssq_st[nf]; v1 += __shfl_xor(v1, 16); v1 += __shfl_xor(v1, 32);
      float v2 = ssum_ts[nf]; v2 += __shfl_xor(v2, 16); v2 += __shfl_xor(v2, 32);
      float v3 = sssq_ts[nf]; v3 += __shfl_xor(v3, 16); v3 += __shfl_xor(v3, 32);
      if (lq == 0) {
        int ch = 16 * nf + lr;
        atomicAdd(&stats2[ch], v0);
        atomicAdd(&stats2[128 + ch], v1);
        atomicAdd(&stats2[256 + ch], v2);
        atomicAdd(&stats2[384 + ch], v3);
      }
    }
  }
}

__global__ void bn_finalize(const float* __restrict__ sum, const float* __restrict__ ssq,
                            float invN, const float* __restrict__ g,
                            const float* __restrict__ be,
                            float* __restrict__ sc, float* __restrict__ sh) {
  int j = threadIdx.x;
  float m = sum[j] * invN;
  float v = ssq[j] * invN - m * m;
  float s = g[j] * rsqrtf(v + EPS_BN);
  sc[j] = s;
  sh[j] = be[j] - m * s;
}

__global__ __launch_bounds__(256) void bn_relu_out(
    const float* __restrict__ U2, const float* __restrict__ scsh,
    float* __restrict__ out, long total) {
  long i = (long)blockIdx.x * blockDim.x + threadIdx.x;
  long stride = (long)gridDim.x * blockDim.x;
  for (; i < total; i += stride) {
    int j = (int)(i & 127);
    out[i] = fmaxf(fmaf(U2[i], scsh[j], scsh[128 + j]), 0.f);
  }
}

extern "C" void kernel_launch(void* const* d_in, const int* in_sizes, int n_in,
                              void* d_out, int out_size, void* d_ws, size_t ws_size,
                              hipStream_t stream) {
  const float* h    = (const float*)d_in[0];
  const int*   ei   = (const int*)d_in[1];
  const float* ea   = (const float*)d_in[2];
  const float* mW1  = (const float*)d_in[3];
  const float* mg1  = (const float*)d_in[5];
  const float* mbe1 = (const float*)d_in[6];
  const float* mW2  = (const float*)d_in[7];
  const float* mg2  = (const float*)d_in[9];
  const float* mbe2 = (const float*)d_in[10];
  const float* uW1  = (const float*)d_in[11];
  const float* ug1  = (const float*)d_in[13];
  const float* ube1 = (const float*)d_in[14];
  const float* uW2  = (const float*)d_in[15];
  const float* ug2  = (const float*)d_in[17];
  const float* ube2 = (const float*)d_in[18];

  int n = in_sizes[0] / 128;
  long E = (long)(in_sizes[1] / 2);
  const int* SRC = ei;
  const int* DST = ei + E;
  const float* W1e = mW1 + 256 * 128;

  size_t nf = (size_t)n * 128;  // elements per node buffer
  float* P    = (float*)d_ws;               // later u1
  float* Q    = P + nf;                     // later u2
  float* a_st = Q + nf;                     // later u1' (bf16 reuse)
  float* a_ts = a_st + nf;
  float* st   = a_ts + nf;
  // stats: [0..511] bn1  [512..1023] bn2  [1024..1535] bn3/bn4
  //        [1536..2047] sc1  [2048..2559] sc2  [2560..3071] sc3/sc4

  char* fastbase = (char*)(st + 3072);
  unsigned short* Pst = (unsigned short*)fastbase;
  unsigned short* Qst = Pst + nf;
  unsigned short* Pts = Qst + nf;
  unsigned short* Qts = Pts + nf;
  unsigned short* Rst = Qts + nf;
  unsigned short* Rts = Rst + (size_t)E * 128;
  size_t need = (size_t)((char*)(Rts + (size_t)E * 128) - (char*)d_ws);
  bool fast = (ws_size >= need);

  float invE = 1.0f / (float)E;
  float invN = 1.0f / (float)n;
  int nblk = (n + 63) / 64;

  // zero a_st, a_ts, stats
  hipMemsetAsync((char*)d_ws + 2 * nf * sizeof(float), 0,
                 (2 * nf + 3072) * sizeof(float), stream);

  // P = h @ W1a, Q = h @ W1b  (MFMA)
  node_mfma<false><<<nblk, 256, 0, stream>>>(h, nullptr, nullptr, mW1, 1.f, 0.f, 0.f,
                                             P, n, 0, nullptr, nullptr, 1);
  node_mfma<false><<<nblk, 256, 0, stream>>>(h, nullptr, nullptr, mW1 + 16384, 1.f, 0.f, 0.f,
                                             Q, n, 0, nullptr, nullptr, 1);

  // BN1 stats over raw z
  msg_stats1<<<2048, 256, 0, stream>>>(P, Q, ea, W1e, SRC, DST, E, st);
  bn_finalize<<<1, 128, 0, stream>>>(st + 0,   st + 128, invE, mg1, mbe1, st + 1536, st + 1664);
  bn_finalize<<<1, 128, 0, stream>>>(st + 256, st + 384, invE, mg1, mbe1, st + 1792, st + 1920);

  if (fast) {
    // prescaled bf16 tables + scaled R
    prescale_pq<<<2048, 256, 0, stream>>>(P, st + 1536, st + 1792,
                                          (unsigned*)Pst, (unsigned*)Pts, n);
    prescale_pq<<<2048, 256, 0, stream>>>(Q, st + 1536, st + 1792,
                                          (unsigned*)Qst, (unsigned*)Qts, n);
    rmat_scaled<<<2048, 256, 0, stream>>>(ea, W1e, st + 1536,
                                          (unsigned*)Rst, (unsigned*)Rts, E);
    msg2<false><<<2048, 256, 0, stream>>>(Pst, Qst, Pts, Qts, Rst, Rts, mW2,
                                          SRC, DST, E, nullptr, st + 512, nullptr, nullptr);
    bn_finalize<<<1, 128, 0, stream>>>(st + 512, st + 640, invE, mg2, mbe2, st + 2048, st + 2176);
    bn_finalize<<<1, 128, 0, stream>>>(st + 768, st + 896, invE, mg2, mbe2, st + 2304, st + 2432);
    msg2<true><<<2048, 256, 0, stream>>>(Pst, Qst, Pts, Qts, Rst, Rts, mW2,
                                         SRC, DST, E, st + 2048, nullptr, a_st, a_ts);
  } else {
    msg_mfma_kernel<false><<<1024, 256, 0, stream>>>(
        P, Q, ea, W1e, mW2, SRC, DST, E, st + 1536, nullptr, st + 512, nullptr, nullptr);
    bn_finalize<<<1, 128, 0, stream>>>(st + 512, st + 640, invE, mg2, mbe2, st + 2048, st + 2176);
    bn_finalize<<<1, 128, 0, stream>>>(st + 768, st + 896, invE, mg2, mbe2, st + 2304, st + 2432);
    msg_mfma_kernel<true><<<1024, 256, 0, stream>>>(
        P, Q, ea, W1e, mW2, SRC, DST, E, st + 1536, st + 2048, nullptr, a_st, a_ts);
  }

  // u1 = h@uW1a + 0.5*a_st@uW1b + 0.5*a_ts@uW1c  (3-chunk MFMA, stats) -> P
  node_mfma<false><<<nblk, 256, 0, stream>>>(h, a_st, a_ts, uW1, 1.f, 0.5f, 0.5f,
                                             P, n, 1, st + 1024, st + 1152, 3);
  bn_finalize<<<1, 128, 0, stream>>>(st + 1024, st + 1152, invN, ug1, ube1, st + 2560, st + 2688);

  // u1' = bf16(relu(bn3(u1))) -> a_st region ; u2 = u1' @ uW2 (stats) -> Q
  unsigned short* u1p = (unsigned short*)a_st;
  prescale_relu<<<2048, 256, 0, stream>>>(P, st + 2560, (unsigned*)u1p, n);
  node_mfma<true><<<nblk, 256, 0, stream>>>(u1p, nullptr, nullptr, uW2, 1.f, 0.f, 0.f,
                                            Q, n, 1, st + 1280, st + 1408, 1);
  bn_finalize<<<1, 128, 0, stream>>>(st + 1280, st + 1408, invN, ug2, ube2, st + 2816, st + 2944);

  bn_relu_out<<<2048, 256, 0, stream>>>(Q, st + 2816, (float*)d_out, (long)n * 128);
}